// Round 3
// baseline (3689.961 us; speedup 1.0000x reference)
//
#include <hip/hip_runtime.h>
#include <hip/hip_bf16.h>
#include <math.h>

// ---------------------------------------------------------------------------
// Dims (fixed by the reference)
// ---------------------------------------------------------------------------
#define BB    1024      // batch
#define NCAND 100000    // candidates
#define DD    256       // d_main
#define CC    96        // context size
#define HH    8         // heads
#define DH    32        // head dim
#define NBLK  2
#define DENC  512
#define DFF   1024
#define NNUM  64
#define NCLS  10
#define CHQ   256       // query chunk for sims buffer

// ---------------------------------------------------------------------------
// Generic fp32 tiled GEMM: C[M,N] = act(A[M,K] @ B + bias) [+ res]
// TB: B is N-major (N x K, take dot of rows)  else K x N row-major.
// M must be a multiple of 64 and K a multiple of 16 (true for all call sites).
// N is masked.
// ---------------------------------------------------------------------------
#define BM 64
#define BN 64
#define BK 16

template <bool TB, bool RELU, bool RES>
__global__ __launch_bounds__(256) void gemm_k(const float* __restrict__ A,
                                              const float* __restrict__ B,
                                              const float* __restrict__ bias,
                                              const float* __restrict__ res,
                                              float* __restrict__ C,
                                              int M, int N, int K) {
    __shared__ __align__(16) float As[BK][BM + 4];
    __shared__ __align__(16) float Bs[BK][BN + 4];
    const int tid = threadIdx.x;
    const int bm = blockIdx.y * BM;
    const int bn = blockIdx.x * BN;
    const int tm = (tid >> 4) << 2;   // 0..60
    const int tn = (tid & 15) << 2;   // 0..60

    float acc[4][4] = {};

    for (int k0 = 0; k0 < K; k0 += BK) {
#pragma unroll
        for (int l = 0; l < 4; ++l) {
            int lin = l * 256 + tid;
            int m = lin >> 4;
            int k = lin & 15;
            As[k][m] = A[(size_t)(bm + m) * K + k0 + k];
        }
#pragma unroll
        for (int l = 0; l < 4; ++l) {
            int lin = l * 256 + tid;
            if (TB) {
                int n = lin >> 4;
                int k = lin & 15;
                int gn = bn + n;
                Bs[k][n] = (gn < N) ? B[(size_t)gn * K + k0 + k] : 0.f;
            } else {
                int k = lin >> 6;
                int n = lin & 63;
                int gn = bn + n;
                Bs[k][n] = (gn < N) ? B[(size_t)(k0 + k) * N + gn] : 0.f;
            }
        }
        __syncthreads();
#pragma unroll
        for (int k = 0; k < BK; ++k) {
            float4 a4 = *(const float4*)&As[k][tm];
            float4 b4 = *(const float4*)&Bs[k][tn];
            float av[4] = {a4.x, a4.y, a4.z, a4.w};
            float bv[4] = {b4.x, b4.y, b4.z, b4.w};
#pragma unroll
            for (int i = 0; i < 4; ++i)
#pragma unroll
                for (int j = 0; j < 4; ++j) acc[i][j] += av[i] * bv[j];
        }
        __syncthreads();
    }

#pragma unroll
    for (int i = 0; i < 4; ++i) {
        int r = bm + tm + i;
#pragma unroll
        for (int j = 0; j < 4; ++j) {
            int c = bn + tn + j;
            if (c < N) {
                float v = acc[i][j];
                if (bias) v += bias[c];
                if (RELU) v = fmaxf(v, 0.f);
                if (RES) v += res[(size_t)r * N + c];
                C[(size_t)r * N + c] = v;
            }
        }
    }
}

// ---------------------------------------------------------------------------
// LayerNorm over D=256 (one block per row)
// ---------------------------------------------------------------------------
__global__ __launch_bounds__(256) void ln_k(const float* __restrict__ x,
                                            const float* __restrict__ s,
                                            const float* __restrict__ b,
                                            float* __restrict__ o) {
    __shared__ float red[256];
    const int row = blockIdx.x, tid = threadIdx.x;
    float v = x[(size_t)row * DD + tid];
    red[tid] = v;
    __syncthreads();
    for (int st = 128; st > 0; st >>= 1) {
        if (tid < st) red[tid] += red[tid + st];
        __syncthreads();
    }
    float mean = red[0] * (1.f / DD);
    __syncthreads();
    float d = v - mean;
    red[tid] = d * d;
    __syncthreads();
    for (int st = 128; st > 0; st >>= 1) {
        if (tid < st) red[tid] += red[tid + st];
        __syncthreads();
    }
    float var = red[0] * (1.f / DD);
    o[(size_t)row * DD + tid] = d / sqrtf(var + 1e-5f) * s[tid] + b[tid];
}

// ---------------------------------------------------------------------------
// Row L2-normalize (D=256)
// ---------------------------------------------------------------------------
__global__ __launch_bounds__(256) void l2norm_k(const float* __restrict__ in,
                                                float* __restrict__ out) {
    __shared__ float red[256];
    const int row = blockIdx.x, tid = threadIdx.x;
    float v = in[(size_t)row * DD + tid];
    red[tid] = v * v;
    __syncthreads();
    for (int st = 128; st > 0; st >>= 1) {
        if (tid < st) red[tid] += red[tid + st];
        __syncthreads();
    }
    float inv = 1.f / sqrtf(red[0]);
    out[(size_t)row * DD + tid] = v * inv;
}

// ---------------------------------------------------------------------------
// Exact top-96 per query over a stored fp32 sims row (monotone-key radix
// select: 8-bit pass, then 8-bit refine, then exact fp32 tie-break).
// ---------------------------------------------------------------------------
__device__ inline unsigned key32(float x) {
    unsigned u = __float_as_uint(x);
    return (u & 0x80000000u) ? ~u : (u | 0x80000000u);
}

__global__ __launch_bounds__(256) void topk_k(const float* __restrict__ sims,
                                              int* __restrict__ idxout, int qo) {
    __shared__ unsigned hist[256];
    __shared__ float tval[1024];
    __shared__ int tidxs[1024];
    __shared__ unsigned s_b1, s_above, s_T16;
    __shared__ unsigned cnt_def, cnt_tie;
    __shared__ float rv[256];
    __shared__ int rj[256];

    const int tid = threadIdx.x;
    const float* row = sims + (size_t)blockIdx.x * NCAND;

    // pass 1: hist of top byte of key
    hist[tid] = 0;
    __syncthreads();
    for (int j = tid; j < NCAND; j += 256) atomicAdd(&hist[key32(row[j]) >> 24], 1u);
    __syncthreads();
    if (tid == 0) {
        unsigned cum = 0;
        int b1 = 0;
        for (int t = 255; t >= 0; --t) {
            if (cum + hist[t] >= CC) { b1 = t; break; }
            cum += hist[t];
        }
        s_b1 = (unsigned)b1;
        s_above = cum;   // count strictly above bin b1
    }
    __syncthreads();
    unsigned b1 = s_b1;
    hist[tid] = 0;
    __syncthreads();
    // pass 2: refine second byte within bin b1
    for (int j = tid; j < NCAND; j += 256) {
        unsigned k = key32(row[j]);
        if ((k >> 24) == b1) atomicAdd(&hist[(k >> 16) & 255u], 1u);
    }
    __syncthreads();
    if (tid == 0) {
        unsigned cum = s_above;
        int b2 = 0;
        for (int t = 255; t >= 0; --t) {
            if (cum + hist[t] >= CC) { b2 = t; break; }
            cum += hist[t];
        }
        s_T16 = (b1 << 8) | (unsigned)b2;
        s_above = cum;   // count with 16-bit key strictly > T16 (< 96)
        cnt_def = 0;
        cnt_tie = 0;
    }
    __syncthreads();
    const unsigned T16 = s_T16;
    int* myout = idxout + (size_t)(qo + blockIdx.x) * CC;
    // pass 3: compact definite winners; gather boundary ties
    for (int j = tid; j < NCAND; j += 256) {
        unsigned k16 = key32(row[j]) >> 16;
        if (k16 > T16) {
            unsigned p = atomicAdd(&cnt_def, 1u);
            myout[p] = j;
        } else if (k16 == T16) {
            unsigned p = atomicAdd(&cnt_tie, 1u);
            if (p < 1024u) { tval[p] = row[j]; tidxs[p] = j; }
        }
    }
    __syncthreads();
    const int base = (int)cnt_def;
    const int rem = CC - base;
    const int nt = (int)(cnt_tie < 1024u ? cnt_tie : 1024u);
    // pass 4: exact fp32 selection of the remaining slots among ties
    for (int r = 0; r < rem; ++r) {
        float bvv = -1e30f;
        int bj = -1;
        for (int t = tid; t < nt; t += 256)
            if (tval[t] > bvv) { bvv = tval[t]; bj = t; }
        rv[tid] = bvv;
        rj[tid] = bj;
        __syncthreads();
        for (int st = 128; st > 0; st >>= 1) {
            if (tid < st && rv[tid + st] > rv[tid]) { rv[tid] = rv[tid + st]; rj[tid] = rj[tid + st]; }
            __syncthreads();
        }
        if (tid == 0) {
            myout[base + r] = tidxs[rj[0]];
            tval[rj[0]] = -1e30f;
        }
        __syncthreads();
    }
}

// ---------------------------------------------------------------------------
// ctx[b,c,:] = candidate_k[idx[b,c],:] + label_emb[candidate_y[idx[b,c]],:]
// ---------------------------------------------------------------------------
__global__ __launch_bounds__(256) void ctx_k(const int* __restrict__ idx,
                                             const float* __restrict__ ck,
                                             const int* __restrict__ cy,
                                             const float* __restrict__ le,
                                             float* __restrict__ ctx) {
    const int row = blockIdx.x, tid = threadIdx.x;
    const int i = idx[row];
    const int y = cy[i];
    ctx[(size_t)row * DD + tid] = ck[(size_t)i * DD + tid] + le[(size_t)y * DD + tid];
}

// ---------------------------------------------------------------------------
// Wf[(h*256+e), f] = sum_d wv[e, h*32+d] * wo[h*32+d, f]
// ---------------------------------------------------------------------------
__global__ __launch_bounds__(256) void wfuse_k(const float* __restrict__ wv,
                                               const float* __restrict__ wo,
                                               float* __restrict__ Wf) {
    const int r = blockIdx.x;          // h*256 + e
    const int h = r >> 8, e = r & 255;
    const int f = threadIdx.x;
    float acc = 0.f;
#pragma unroll
    for (int d = 0; d < DH; ++d)
        acc += wv[(size_t)e * DD + h * DH + d] * wo[(size_t)(h * DH + d) * DD + f];
    Wf[(size_t)r * DD + f] = acc;
}

// c0[f] = bv @ wo + bo
__global__ __launch_bounds__(256) void c0_k(const float* __restrict__ bv,
                                            const float* __restrict__ wo,
                                            const float* __restrict__ bo,
                                            float* __restrict__ c0) {
    const int f = threadIdx.x;
    float acc = bo[f];
    for (int r = 0; r < DD; ++r) acc += bv[r] * wo[(size_t)r * DD + f];
    c0[f] = acc;
}

// ---------------------------------------------------------------------------
// Fused attention (per batch row b):
//   t[h,e]   = sum_d q[b,h*32+d] * wk[e, h*32+d]          (bk drops in softmax)
//   s[h,c]   = scale * sum_e ctx[b,c,e] * t[h,e]
//   a        = softmax_c(s)
//   m[h,e]   = sum_c a[h,c] * ctx[b,c,e]   -> mout[b, h*256+e]
// ---------------------------------------------------------------------------
__global__ __launch_bounds__(256) void attn_k(const float* __restrict__ qb,
                                              const float* __restrict__ wk,
                                              const float* __restrict__ ctx,
                                              float* __restrict__ mout) {
    __shared__ float qs[DD];
    __shared__ float ts[HH * DD];
    __shared__ float ss[HH * CC];
    const int b = blockIdx.x, tid = threadIdx.x;
    qs[tid] = qb[(size_t)b * DD + tid];
    __syncthreads();

    for (int idx = tid; idx < HH * DD; idx += 256) {
        const int h = idx >> 8, e = idx & 255;
        float acc = 0.f;
#pragma unroll
        for (int d = 0; d < DH; ++d) acc += qs[h * DH + d] * wk[(size_t)e * DD + h * DH + d];
        ts[idx] = acc;
    }
    __syncthreads();

    const float scale = 0.17677669529663687f;  // 1/sqrt(32)
    const float* cb = ctx + (size_t)b * CC * DD;
    for (int o = tid; o < HH * CC; o += 256) {
        const int c = o >> 3, h = o & 7;
        const float* cr = cb + (size_t)c * DD;
        const float* th = ts + h * DD;
        float acc = 0.f;
        for (int e = 0; e < DD; ++e) acc += cr[e] * th[e];
        ss[h * CC + c] = acc * scale;
    }
    __syncthreads();

    if (tid < HH) {
        const int h = tid;
        float mx = -1e30f;
        for (int c = 0; c < CC; ++c) mx = fmaxf(mx, ss[h * CC + c]);
        float sum = 0.f;
        for (int c = 0; c < CC; ++c) {
            float e = expf(ss[h * CC + c] - mx);
            ss[h * CC + c] = e;
            sum += e;
        }
        float inv = 1.f / sum;
        for (int c = 0; c < CC; ++c) ss[h * CC + c] *= inv;
    }
    __syncthreads();

    float acc[HH] = {};
    for (int c = 0; c < CC; ++c) {
        float v = cb[(size_t)c * DD + tid];
#pragma unroll
        for (int h = 0; h < HH; ++h) acc[h] += ss[h * CC + c] * v;
    }
#pragma unroll
    for (int h = 0; h < HH; ++h) mout[(size_t)b * (HH * DD) + h * DD + tid] = acc[h];
}

// ---------------------------------------------------------------------------
// Host launcher
// ---------------------------------------------------------------------------
extern "C" void kernel_launch(void* const* d_in, const int* in_sizes, int n_in,
                              void* d_out, int out_size, void* d_ws, size_t ws_size,
                              hipStream_t stream) {
    (void)in_sizes; (void)n_in; (void)out_size; (void)ws_size;
    const float* x_num  = (const float*)d_in[0];
    const float* cand_k = (const float*)d_in[1];
    const int*   cand_y = (const int*)d_in[2];
    const float* enc_w0 = (const float*)d_in[3];
    const float* enc_b0 = (const float*)d_in[4];
    const float* enc_ln_s = (const float*)d_in[5];
    const float* enc_ln_b = (const float*)d_in[6];
    const float* enc_w1 = (const float*)d_in[7];
    const float* enc_b1 = (const float*)d_in[8];
    const float* enc_w2 = (const float*)d_in[9];
    const float* enc_b2 = (const float*)d_in[10];
    const float* label_emb = (const float*)d_in[11];
    const float* ln1_s = (const float*)d_in[12];
    const float* ln1_b = (const float*)d_in[13];
    const float* wq = (const float*)d_in[14];
    const float* bq = (const float*)d_in[15];
    const float* wk = (const float*)d_in[16];
    // d_in[17] = bk : constant shift per (b,h) inside softmax -> drops out
    const float* wv = (const float*)d_in[18];
    const float* bv = (const float*)d_in[19];
    const float* wo = (const float*)d_in[20];
    const float* bo = (const float*)d_in[21];
    const float* ln2_s = (const float*)d_in[22];
    const float* ln2_b = (const float*)d_in[23];
    const float* fw1 = (const float*)d_in[24];
    const float* fb1 = (const float*)d_in[25];
    const float* fw2 = (const float*)d_in[26];
    const float* fb2 = (const float*)d_in[27];
    const float* head_w = (const float*)d_in[28];
    const float* head_b = (const float*)d_in[29];
    float* out = (float*)d_out;

    char* ws = (char*)d_ws;
    size_t off = 0;
    auto alloc = [&](size_t bytes) -> void* {
        void* p = ws + off;
        off += (bytes + 255) & ~(size_t)255;
        return p;
    };
    float* big  = (float*)alloc((size_t)CHQ * NCAND * 4);   // sims chunk, reused as ctx
    float* h0   = (float*)alloc((size_t)BB * DD * 4);
    float* h1   = (float*)alloc((size_t)BB * DENC * 4);
    float* hln  = (float*)alloc((size_t)BB * DD * 4);
    float* x    = (float*)alloc((size_t)BB * DD * 4);       // query, then residual stream
    float* qbuf = (float*)alloc((size_t)BB * DD * 4);
    int*   idxb = (int*)alloc((size_t)BB * CC * 4);
    float* mbuf = (float*)alloc((size_t)BB * HH * DD * 4);
    float* Wf   = (float*)alloc((size_t)HH * DD * DD * 4);
    float* c0   = (float*)alloc(DD * 4);
    float* ffh  = (float*)alloc((size_t)BB * DFF * 4);
    float* ctx  = big;

    dim3 blk(256);

    // ---- encoder ----
    gemm_k<false, false, false><<<dim3(DD / BN, BB / BM), blk, 0, stream>>>(
        x_num, enc_w0, enc_b0, nullptr, h0, BB, DD, NNUM);
    for (int i = 0; i < NBLK; ++i) {
        ln_k<<<BB, blk, 0, stream>>>(h0, enc_ln_s + i * DD, enc_ln_b + i * DD, hln);
        gemm_k<false, true, false><<<dim3(DENC / BN, BB / BM), blk, 0, stream>>>(
            hln, enc_w1 + (size_t)i * DD * DENC, enc_b1 + i * DENC, nullptr, h1, BB, DENC, DD);
        gemm_k<false, false, false><<<dim3(DD / BN, BB / BM), blk, 0, stream>>>(
            h1, enc_w2 + (size_t)i * DENC * DD, enc_b2 + i * DD, nullptr, h0, BB, DD, DENC);
    }
    l2norm_k<<<BB, blk, 0, stream>>>(h0, x);  // x = query

    // ---- retrieval: sims (fp32, chunked) + exact top-96 ----
    for (int ci = 0; ci < BB / CHQ; ++ci) {
        const int qo = ci * CHQ;
        gemm_k<true, false, false><<<dim3((NCAND + BN - 1) / BN, CHQ / BM), blk, 0, stream>>>(
            x + (size_t)qo * DD, cand_k, nullptr, nullptr, big, CHQ, NCAND, DD);
        topk_k<<<CHQ, blk, 0, stream>>>(big, idxb, qo);
    }
    ctx_k<<<BB * CC, blk, 0, stream>>>(idxb, cand_k, cand_y, label_emb, ctx);

    // ---- transformer mixer (associativity-restructured attention) ----
    for (int i = 0; i < NBLK; ++i) {
        const size_t W = (size_t)i * DD * DD;
        ln_k<<<BB, blk, 0, stream>>>(x, ln1_s + i * DD, ln1_b + i * DD, hln);
        gemm_k<false, false, false><<<dim3(DD / BN, BB / BM), blk, 0, stream>>>(
            hln, wq + W, bq + i * DD, nullptr, qbuf, BB, DD, DD);
        wfuse_k<<<HH * DD, blk, 0, stream>>>(wv + W, wo + W, Wf);
        c0_k<<<1, blk, 0, stream>>>(bv + i * DD, wo + W, bo + i * DD, c0);
        attn_k<<<BB, blk, 0, stream>>>(qbuf, wk + W, ctx, mbuf);
        gemm_k<false, false, true><<<dim3(DD / BN, BB / BM), blk, 0, stream>>>(
            mbuf, Wf, c0, x, x, BB, DD, HH * DD);
        ln_k<<<BB, blk, 0, stream>>>(x, ln2_s + i * DD, ln2_b + i * DD, hln);
        gemm_k<false, true, false><<<dim3(DFF / BN, BB / BM), blk, 0, stream>>>(
            hln, fw1 + (size_t)i * DD * DFF, fb1 + i * DFF, nullptr, ffh, BB, DFF, DD);
        gemm_k<false, false, true><<<dim3(DD / BN, BB / BM), blk, 0, stream>>>(
            ffh, fw2 + (size_t)i * DFF * DD, fb2 + i * DD, x, x, BB, DD, DFF);
    }

    // ---- head ----
    gemm_k<false, false, false><<<dim3(1, BB / BM), blk, 0, stream>>>(
        x, head_w, head_b, nullptr, out, BB, NCLS, DD);
}